// Round 3
// baseline (317.851 us; speedup 1.0000x reference)
//
#include <hip/hip_runtime.h>

typedef float vfloat4 __attribute__((ext_vector_type(4)));

#define SCAN_BLOCK 1024
#define PER4MAX 4   // supports S up to 4*1024*PER4MAX = 65536 (S=4096 -> per4=1)

// Kernel 1: per-batch scan over merge flags -> token segment boundaries.
// tok_start[b*(S+1) + t] = first subtoken index of token t; tok_start[..+ntok] = len.
// int4-vectorized merge read cached in registers (single global pass),
// wave-level __shfl_up scan + one __syncthreads over 16 wave partials.
__global__ void __launch_bounds__(SCAN_BLOCK)
scan_kernel(const int* __restrict__ merge,
            const int* __restrict__ lengths,
            int* __restrict__ tok_start,
            int* __restrict__ ntok_arr,
            int S) {
    const int b    = blockIdx.x;
    const int tid  = threadIdx.x;
    const int lane = tid & 63;
    const int wid  = tid >> 6;                 // 16 waves per block

    int len = lengths[b];
    if (len < 1) len = 1;
    if (len > S) len = S;

    const int  S4    = S >> 2;                                  // int4 chunks per row (S%4==0)
    const int  per4  = (S4 + SCAN_BLOCK - 1) / SCAN_BLOCK;      // chunks per thread (1 @ S=4096)
    const int4* mrow4 = reinterpret_cast<const int4*>(merge + (size_t)b * S);
    const int  base4 = tid * per4;                              // contiguous ownership per thread

    // pass 1: vectorized load + per-thread count of "new token" flags.
    int4 mv[PER4MAX];
    int tsum = 0;
    #pragma unroll
    for (int c = 0; c < PER4MAX; ++c) {
        if (c < per4) {
            const int chunk = base4 + c;
            int4 m = {1, 1, 1, 1};
            if (chunk < S4) m = mrow4[chunk];
            mv[c] = m;
            const int s0 = chunk << 2;
            tsum += (s0 + 0 < len) && (s0 == 0 || m.x == 0);
            tsum += (s0 + 1 < len) && (m.y == 0);
            tsum += (s0 + 2 < len) && (m.z == 0);
            tsum += (s0 + 3 < len) && (m.w == 0);
        }
    }

    // wave-level inclusive scan (6 shfl steps, no barriers)
    int inc = tsum;
    #pragma unroll
    for (int off = 1; off < 64; off <<= 1) {
        int n = __shfl_up(inc, off, 64);
        if (lane >= off) inc += n;
    }

    // cross-wave: one barrier over 16 partials, each thread reduces locally
    __shared__ int wpart[SCAN_BLOCK / 64];
    if (lane == 63) wpart[wid] = inc;
    __syncthreads();
    int wexc = 0, total = 0;
    #pragma unroll
    for (int w = 0; w < SCAN_BLOCK / 64; ++w) {
        const int p = wpart[w];
        wexc  += (w < wid) ? p : 0;
        total += p;
    }
    int run = wexc + (inc - tsum);   // exclusive prefix for this thread's range

    // pass 2: emit start offsets from the register-cached flags (no global re-read)
    int* ts = tok_start + (size_t)b * (S + 1);
    #pragma unroll
    for (int c = 0; c < PER4MAX; ++c) {
        if (c < per4) {
            const int chunk = base4 + c;
            if (chunk < S4) {
                const int4 m = mv[c];
                const int s0 = chunk << 2;
                if ((s0 + 0 < len) && (s0 == 0 || m.x == 0)) ts[run++] = s0 + 0;
                if ((s0 + 1 < len) && (m.y == 0))            ts[run++] = s0 + 1;
                if ((s0 + 2 < len) && (m.z == 0))            ts[run++] = s0 + 2;
                if ((s0 + 3 < len) && (m.w == 0))            ts[run++] = s0 + 3;
            }
        }
    }

    if (tid == 0) {
        ntok_arr[b] = total;
        ts[total] = len;   // sentinel end for the last token
    }
}

// Kernel 2 (v3: persistent grid-stride). One WAVE per output row (b, t), waves
// grid-stride over flat row index idx = b*S + t. 2048 blocks x 4 waves = 8192
// waves -> 8 rows/wave, full 32-wave/CU occupancy, no per-block retire barrier
// coupling long segments to short ones, 8x fewer block dispatches.
// Lane owns float4s {lane, lane+64, lane+128} of the 192-float4 row; segment
// loop unrolled x4 -> up to 12 independent nontemporal loads in flight.
__global__ void __launch_bounds__(256)
mean_kernel(const vfloat4* __restrict__ hidden,
            const int* __restrict__ tok_start,
            const int* __restrict__ ntok_arr,
            vfloat4* __restrict__ out,
            int S, int nrows) {
    const int wave   = threadIdx.x >> 6;
    const int lane   = threadIdx.x & 63;
    const int nwaves = gridDim.x << 2;

    for (int idx = (blockIdx.x << 2) + wave; idx < nrows; idx += nwaves) {
        const int b = idx / S;           // magic-mul, cheap
        const int t = idx - b * S;

        vfloat4* op = out + (size_t)idx * 192 + lane;

        if (t >= ntok_arr[b]) {          // padding row: zeros
            const vfloat4 z = {0.f, 0.f, 0.f, 0.f};
            __builtin_nontemporal_store(z, op);
            __builtin_nontemporal_store(z, op + 64);
            __builtin_nontemporal_store(z, op + 128);
            continue;
        }

        const int* ts   = tok_start + (size_t)b * (S + 1);
        const int start = ts[t];
        const int end   = ts[t + 1];

        const vfloat4* hp = hidden + (size_t)b * S * 192 + lane;

        vfloat4 a0 = {0.f, 0.f, 0.f, 0.f};
        vfloat4 a1 = a0, a2 = a0;

#define ACC_ROW(ROW)                                                     \
        {                                                                \
            const vfloat4* p = hp + (size_t)(ROW) * 192;                 \
            vfloat4 v0 = __builtin_nontemporal_load(p);                  \
            vfloat4 v1 = __builtin_nontemporal_load(p + 64);             \
            vfloat4 v2 = __builtin_nontemporal_load(p + 128);            \
            a0 += v0;                                                    \
            a1 += v1;                                                    \
            a2 += v2;                                                    \
        }

        int s = start;
        for (; s + 4 <= end; s += 4) {   // wave-uniform bounds -> uniform branch
            ACC_ROW(s)
            ACC_ROW(s + 1)
            ACC_ROW(s + 2)
            ACC_ROW(s + 3)
        }
        for (; s < end; ++s) {
            ACC_ROW(s)
        }
#undef ACC_ROW

        const float inv = 1.0f / (float)(end - start);
        a0 *= inv;
        a1 *= inv;
        a2 *= inv;
        __builtin_nontemporal_store(a0, op);
        __builtin_nontemporal_store(a1, op + 64);
        __builtin_nontemporal_store(a2, op + 128);
    }
}

extern "C" void kernel_launch(void* const* d_in, const int* in_sizes, int n_in,
                              void* d_out, int out_size, void* d_ws, size_t ws_size,
                              hipStream_t stream) {
    const float* hidden  = (const float*)d_in[0];
    const int*   merge   = (const int*)d_in[1];
    const int*   lengths = (const int*)d_in[2];

    const int B  = in_sizes[2];          // 16
    const int BS = in_sizes[1];          // B*S
    const int S  = BS / B;               // 4096
    // D assumed 768 (vfloat4 x 192 per row), per reference shapes.

    int* tok_start = (int*)d_ws;                         // B*(S+1) ints (~262 KB)
    int* ntok      = tok_start + (size_t)B * (S + 1);    // B ints

    scan_kernel<<<B, SCAN_BLOCK, 0, stream>>>(merge, lengths, tok_start, ntok, S);

    const int nrows  = BS;                                // 65536 output rows
    const int blocks = 2048;                              // 8 blocks/CU, 32 waves/CU
    mean_kernel<<<blocks, 256, 0, stream>>>((const vfloat4*)hidden,
                                            tok_start, ntok,
                                            (vfloat4*)d_out, S, nrows);
}

// Round 4
// 309.180 us; speedup vs baseline: 1.0280x; 1.0280x over previous
//
#include <hip/hip_runtime.h>

typedef float vfloat4 __attribute__((ext_vector_type(4)));

#define SCAN_BLOCK 1024
#define PER4MAX 4   // supports S up to 4*1024*PER4MAX = 65536 (S=4096 -> per4=1)

// Kernel 1: per-batch scan over merge flags -> token segment boundaries.
// tok_start[b*(S+1) + t] = first subtoken index of token t; tok_start[..+ntok] = len.
// int4-vectorized merge read cached in registers (single global pass),
// wave-level __shfl_up scan + one __syncthreads over 16 wave partials.
__global__ void __launch_bounds__(SCAN_BLOCK)
scan_kernel(const int* __restrict__ merge,
            const int* __restrict__ lengths,
            int* __restrict__ tok_start,
            int* __restrict__ ntok_arr,
            int S) {
    const int b    = blockIdx.x;
    const int tid  = threadIdx.x;
    const int lane = tid & 63;
    const int wid  = tid >> 6;                 // 16 waves per block

    int len = lengths[b];
    if (len < 1) len = 1;
    if (len > S) len = S;

    const int  S4    = S >> 2;                                  // int4 chunks per row (S%4==0)
    const int  per4  = (S4 + SCAN_BLOCK - 1) / SCAN_BLOCK;      // chunks per thread (1 @ S=4096)
    const int4* mrow4 = reinterpret_cast<const int4*>(merge + (size_t)b * S);
    const int  base4 = tid * per4;                              // contiguous ownership per thread

    // pass 1: vectorized load + per-thread count of "new token" flags.
    int4 mv[PER4MAX];
    int tsum = 0;
    #pragma unroll
    for (int c = 0; c < PER4MAX; ++c) {
        if (c < per4) {
            const int chunk = base4 + c;
            int4 m = {1, 1, 1, 1};
            if (chunk < S4) m = mrow4[chunk];
            mv[c] = m;
            const int s0 = chunk << 2;
            tsum += (s0 + 0 < len) && (s0 == 0 || m.x == 0);
            tsum += (s0 + 1 < len) && (m.y == 0);
            tsum += (s0 + 2 < len) && (m.z == 0);
            tsum += (s0 + 3 < len) && (m.w == 0);
        }
    }

    // wave-level inclusive scan (6 shfl steps, no barriers)
    int inc = tsum;
    #pragma unroll
    for (int off = 1; off < 64; off <<= 1) {
        int n = __shfl_up(inc, off, 64);
        if (lane >= off) inc += n;
    }

    // cross-wave: one barrier over 16 partials, each thread reduces locally
    __shared__ int wpart[SCAN_BLOCK / 64];
    if (lane == 63) wpart[wid] = inc;
    __syncthreads();
    int wexc = 0, total = 0;
    #pragma unroll
    for (int w = 0; w < SCAN_BLOCK / 64; ++w) {
        const int p = wpart[w];
        wexc  += (w < wid) ? p : 0;
        total += p;
    }
    int run = wexc + (inc - tsum);   // exclusive prefix for this thread's range

    // pass 2: emit start offsets from the register-cached flags (no global re-read)
    int* ts = tok_start + (size_t)b * (S + 1);
    #pragma unroll
    for (int c = 0; c < PER4MAX; ++c) {
        if (c < per4) {
            const int chunk = base4 + c;
            if (chunk < S4) {
                const int4 m = mv[c];
                const int s0 = chunk << 2;
                if ((s0 + 0 < len) && (s0 == 0 || m.x == 0)) ts[run++] = s0 + 0;
                if ((s0 + 1 < len) && (m.y == 0))            ts[run++] = s0 + 1;
                if ((s0 + 2 < len) && (m.z == 0))            ts[run++] = s0 + 2;
                if ((s0 + 3 < len) && (m.w == 0))            ts[run++] = s0 + 3;
            }
        }
    }

    if (tid == 0) {
        ntok_arr[b] = total;
        ts[total] = len;   // sentinel end for the last token
    }
}

// Kernel 2: one WAVE per output row (b, t). Lane owns float4s {lane, lane+64, lane+128}
// of the 192-float4 row. 4 rows per 256-thread block. Segment loop unrolled x4 ->
// up to 12 independent nontemporal loads in flight per lane (hidden is read exactly
// once globally, output written once -> nt bypasses L2 allocation).
// NOTE (R3 lesson): keep the 16384-block dispatch — the HW dispatcher gives dynamic
// load balancing over geometric-length segments; a persistent static-partition grid
// (2048 blocks x 8 rows/wave) measured 12% SLOWER on mean_kernel (317.9 vs 310.6 total).
__global__ void __launch_bounds__(256)
mean_kernel(const vfloat4* __restrict__ hidden,
            const int* __restrict__ tok_start,
            const int* __restrict__ ntok_arr,
            vfloat4* __restrict__ out,
            int S) {
    const int wave = threadIdx.x >> 6;
    const int lane = threadIdx.x & 63;
    const int t    = (blockIdx.x << 2) + wave;   // token slot within batch
    const int b    = blockIdx.y;
    if (t >= S) return;

    vfloat4* op = out + ((size_t)b * S + t) * 192 + lane;
    const int ntok = ntok_arr[b];

    if (t >= ntok) {   // padding row: zeros (single write pass, no memset needed)
        const vfloat4 z = {0.f, 0.f, 0.f, 0.f};
        __builtin_nontemporal_store(z, op);
        __builtin_nontemporal_store(z, op + 64);
        __builtin_nontemporal_store(z, op + 128);
        return;
    }

    const int* ts   = tok_start + (size_t)b * (S + 1);
    const int start = ts[t];
    const int end   = ts[t + 1];

    const vfloat4* hp = hidden + (size_t)b * S * 192 + lane;

    vfloat4 a0 = {0.f, 0.f, 0.f, 0.f};
    vfloat4 a1 = a0, a2 = a0;

#define ACC_ROW(ROW)                                                     \
    {                                                                    \
        const vfloat4* p = hp + (size_t)(ROW) * 192;                     \
        vfloat4 v0 = __builtin_nontemporal_load(p);                      \
        vfloat4 v1 = __builtin_nontemporal_load(p + 64);                 \
        vfloat4 v2 = __builtin_nontemporal_load(p + 128);                \
        a0 += v0;                                                        \
        a1 += v1;                                                        \
        a2 += v2;                                                        \
    }

    int s = start;
    for (; s + 4 <= end; s += 4) {   // wave-uniform bounds -> uniform branch
        ACC_ROW(s)
        ACC_ROW(s + 1)
        ACC_ROW(s + 2)
        ACC_ROW(s + 3)
    }
    for (; s < end; ++s) {
        ACC_ROW(s)
    }
#undef ACC_ROW

    const float inv = 1.0f / (float)(end - start);
    a0 *= inv;
    a1 *= inv;
    a2 *= inv;
    __builtin_nontemporal_store(a0, op);
    __builtin_nontemporal_store(a1, op + 64);
    __builtin_nontemporal_store(a2, op + 128);
}

extern "C" void kernel_launch(void* const* d_in, const int* in_sizes, int n_in,
                              void* d_out, int out_size, void* d_ws, size_t ws_size,
                              hipStream_t stream) {
    const float* hidden  = (const float*)d_in[0];
    const int*   merge   = (const int*)d_in[1];
    const int*   lengths = (const int*)d_in[2];

    const int B  = in_sizes[2];          // 16
    const int BS = in_sizes[1];          // B*S
    const int S  = BS / B;               // 4096
    // D assumed 768 (vfloat4 x 192 per row), per reference shapes.

    int* tok_start = (int*)d_ws;                         // B*(S+1) ints (~262 KB)
    int* ntok      = tok_start + (size_t)B * (S + 1);    // B ints

    scan_kernel<<<B, SCAN_BLOCK, 0, stream>>>(merge, lengths, tok_start, ntok, S);
    mean_kernel<<<dim3((S + 3) / 4, B), 256, 0, stream>>>((const vfloat4*)hidden,
                                                          tok_start, ntok,
                                                          (vfloat4*)d_out, S);
}